// Round 8
// baseline (31.043 us; speedup 1.0000x reference)
//
#include <hip/hip_runtime.h>

#define HGT 256
#define WID 256
#define NPT 160
#define NBATCH 8
#define RPB 4   // rows per thread; block covers 256 cols x 4 rows

// d_ws layout: float4 pd[NBATCH][NPT] (px*ic, py*ic, a0, a1) | float inv_c[NBATCH]

// Pre-kernel (8 blocks): support radius + normalize + pack.
__global__ __launch_bounds__(256) void rbf_prep_kernel(const float* __restrict__ cpoint,
                                                       const float* __restrict__ alpha,
                                                       float4* __restrict__ pd,
                                                       float* __restrict__ invc) {
    const int b = blockIdx.x;
    const int tid = threadIdx.x;
    __shared__ float2 spts[NPT];
    __shared__ float sred[4];
    __shared__ float s_invc;

    const float2* cp2 = reinterpret_cast<const float2*>(cpoint) + b * NPT;
    const float2* al2 = reinterpret_cast<const float2*>(alpha) + b * NPT;

    if (tid < NPT) spts[tid] = cp2[tid];
    __syncthreads();

    float m = 0.0f;  // idle threads contribute 0 (all min-sq-dists >= 0)
    if (tid < NPT) {
        float minv = 1e10f;
        const float2 pi = spts[tid];
#pragma unroll 8
        for (int j = 0; j < NPT; ++j) {
            float dx = pi.x - spts[j].x;
            float dy = pi.y - spts[j].y;
            float s = fmaf(dy, dy, dx * dx);
            s = (j == tid) ? 1e10f : s;   // mask self-distance (reference: +eye*BIG)
            minv = fminf(minv, s);
        }
        m = minv;
    }
    // wave-level max reduce, then cross-wave via 4 LDS slots (2 barriers total)
#pragma unroll
    for (int off = 32; off > 0; off >>= 1) m = fmaxf(m, __shfl_xor(m, off));
    if ((tid & 63) == 0) sred[tid >> 6] = m;
    __syncthreads();
    if (tid == 0) {
        float mm = fmaxf(fmaxf(sred[0], sred[1]), fmaxf(sred[2], sred[3]));
        s_invc = 1.0f / (2.0f * sqrtf(mm));
        invc[b] = s_invc;
    }
    __syncthreads();
    const float ic = s_invc;
    if (tid < NPT) {
        float2 p = spts[tid];
        float2 a = al2[tid];
        pd[b * NPT + tid] = make_float4(p.x * ic, p.y * ic, a.x, a.y);
    }
}

__device__ __forceinline__ float rdlane(float v, int l) {
    return __int_as_float(__builtin_amdgcn_readlane(__float_as_int(v), l));
}

// Eval kernel: no LDS, no barriers. Candidates live in registers (3 float4/lane),
// cull -> 3 ballot masks (SGPR), survivors iterated via scalar ffs loop + v_readlane.
__global__ __launch_bounds__(256) void rbf_eval_kernel(const float4* __restrict__ pd,
                                                       const float* __restrict__ invc,
                                                       float* __restrict__ out) {
    const int tid = threadIdx.x;
    const int lane = tid & 63;
    const int wv = tid >> 6;
    const int b = blockIdx.x >> 6;        // 64 blocks per batch
    const int blk = blockIdx.x & 63;
    const int h0 = blk * RPB;

    const float inv_c = invc[b];
    const float4* base = pd + b * NPT;

    // candidate chunks: lane holds point r*64+lane (chunk 2 partially valid)
    float4 q0 = base[lane];
    float4 q1 = base[64 + lane];
    const int n2 = 128 + lane;
    const bool v2 = (n2 < NPT);
    float4 q2 = base[v2 ? n2 : 0];

    // wave footprint in normalized coords
    const float wx0 = (float)(wv * 64) * inv_c;
    const float wx1 = (float)(wv * 64 + 63) * inv_c;
    const float wy0 = (float)h0 * inv_c;
    const float wy1 = (float)(h0 + RPB - 1) * inv_c;

#define CULL(q) (fmaf(fmaxf(fmaxf(wx0 - (q).x, (q).x - wx1), 0.0f),              \
                      fmaxf(fmaxf(wx0 - (q).x, (q).x - wx1), 0.0f),              \
                      fmaxf(fmaxf(wy0 - (q).y, (q).y - wy1), 0.0f) *             \
                      fmaxf(fmaxf(wy0 - (q).y, (q).y - wy1), 0.0f)) < 1.0f)

    unsigned long long m0 = __ballot(CULL(q0));
    unsigned long long m1 = __ballot(CULL(q1));
    unsigned long long m2 = __ballot(v2 && CULL(q2));
#undef CULL

    const float xs = (float)tid * inv_c;
    float acc0[RPB], acc1[RPB], ys[RPB];
#pragma unroll
    for (int k = 0; k < RPB; ++k) {
        acc0[k] = 0.0f;
        acc1[k] = 0.0f;
        ys[k] = (float)(h0 + k) * inv_c;
    }

    // per-survivor body: point broadcast into scalars via readlane (wave-uniform l)
#define SBODY(q)                                                  \
    {                                                             \
        const float px = rdlane((q).x, l);                        \
        const float py = rdlane((q).y, l);                        \
        const float pa = rdlane((q).z, l);                        \
        const float pb = rdlane((q).w, l);                        \
        float dx = xs - px;                                       \
        float dx2 = dx * dx;                                      \
        _Pragma("unroll")                                         \
        for (int k = 0; k < RPB; ++k) {                           \
            float dy = ys[k] - py;                                \
            float d2 = fmaf(dy, dy, dx2);                         \
            float d = __builtin_amdgcn_sqrtf(d2);                 \
            float t = fmaxf(1.0f - d, 0.0f);                      \
            float g = fmaf(4.0f, d, 1.0f);                        \
            float t2 = t * t;                                     \
            float wgt = (t2 * t2) * g;                            \
            acc0[k] = fmaf(wgt, pa, acc0[k]);                     \
            acc1[k] = fmaf(wgt, pb, acc1[k]);                     \
        }                                                         \
    }

    while (m0) { const int l = __builtin_ctzll(m0); m0 &= (m0 - 1); SBODY(q0); }
    while (m1) { const int l = __builtin_ctzll(m1); m1 &= (m1 - 1); SBODY(q1); }
    while (m2) { const int l = __builtin_ctzll(m2); m2 &= (m2 - 1); SBODY(q2); }
#undef SBODY

    // out[((b*2 + c)*H + h)*W + x], coalesced across tid
#pragma unroll
    for (int k = 0; k < RPB; ++k) {
        const int h = h0 + k;
        out[((b * 2 + 0) * HGT + h) * WID + tid] = acc0[k];
        out[((b * 2 + 1) * HGT + h) * WID + tid] = acc1[k];
    }
}

extern "C" void kernel_launch(void* const* d_in, const int* in_sizes, int n_in,
                              void* d_out, int out_size, void* d_ws, size_t ws_size,
                              hipStream_t stream) {
    const float* cpoint = (const float*)d_in[0];  // [B, N, 2] f32
    const float* alpha  = (const float*)d_in[1];  // [B, N, 2] f32
    float4* pd  = (float4*)d_ws;                  // [B, N] packed normalized points
    float* invc = (float*)((char*)d_ws + NBATCH * NPT * sizeof(float4));
    float* out  = (float*)d_out;                  // [B, 2, H, W] f32

    rbf_prep_kernel<<<NBATCH, 256, 0, stream>>>(cpoint, alpha, pd, invc);
    rbf_eval_kernel<<<NBATCH * (HGT / RPB), 256, 0, stream>>>(pd, invc, out);
}

// Round 9
// 27.713 us; speedup vs baseline: 1.1201x; 1.1201x over previous
//
#include <hip/hip_runtime.h>

#define HGT 256
#define WID 256
#define NPT 160
#define NBATCH 8
#define RPB 2   // rows per thread; block covers 256 cols x 2 rows; 1024 blocks total

// d_ws layout: float4 pd[NBATCH][NPT] (px*ic, py*ic, a0, a1) | float inv_c[NBATCH]

// Pre-kernel (8 blocks): support radius + normalize + pack.
__global__ __launch_bounds__(256) void rbf_prep_kernel(const float* __restrict__ cpoint,
                                                       const float* __restrict__ alpha,
                                                       float4* __restrict__ pd,
                                                       float* __restrict__ invc) {
    const int b = blockIdx.x;
    const int tid = threadIdx.x;
    __shared__ float2 spts[NPT];
    __shared__ float sred[4];
    __shared__ float s_invc;

    const float2* cp2 = reinterpret_cast<const float2*>(cpoint) + b * NPT;
    const float2* al2 = reinterpret_cast<const float2*>(alpha) + b * NPT;

    if (tid < NPT) spts[tid] = cp2[tid];
    __syncthreads();

    float m = 0.0f;  // idle threads contribute 0 (all min-sq-dists >= 0)
    if (tid < NPT) {
        float minv = 1e10f;
        const float2 pi = spts[tid];
#pragma unroll 8
        for (int j = 0; j < NPT; ++j) {
            float dx = pi.x - spts[j].x;
            float dy = pi.y - spts[j].y;
            float s = fmaf(dy, dy, dx * dx);
            s = (j == tid) ? 1e10f : s;   // mask self-distance (reference: +eye*BIG)
            minv = fminf(minv, s);
        }
        m = minv;
    }
#pragma unroll
    for (int off = 32; off > 0; off >>= 1) m = fmaxf(m, __shfl_xor(m, off));
    if ((tid & 63) == 0) sred[tid >> 6] = m;
    __syncthreads();
    if (tid == 0) {
        float mm = fmaxf(fmaxf(sred[0], sred[1]), fmaxf(sred[2], sred[3]));
        s_invc = 1.0f / (2.0f * sqrtf(mm));
        invc[b] = s_invc;
    }
    __syncthreads();
    const float ic = s_invc;
    if (tid < NPT) {
        float2 p = spts[tid];
        float2 a = al2[tid];
        pd[b * NPT + tid] = make_float4(p.x * ic, p.y * ic, a.x, a.y);
    }
}

// Eval kernel: 1024 blocks (4/CU, 16 waves/CU) for latency hiding. Per-wave
// ballot-compacted LDS survivor list, then branch-free x4-unrolled accumulate.
__global__ __launch_bounds__(256) void rbf_eval_kernel(const float4* __restrict__ pd,
                                                       const float* __restrict__ invc,
                                                       float* __restrict__ out) {
    const int tid = threadIdx.x;
    const int lane = tid & 63;
    const int wv = tid >> 6;
    const int b = blockIdx.x >> 7;        // 128 blocks per batch
    const int blk = blockIdx.x & 127;
    const int h0 = blk * RPB;

    __shared__ float4 wl[4][NPT + 4];     // per-wave compacted list

    const float inv_c = invc[b];
    const float4* base = pd + b * NPT;

    // wave footprint in normalized coords: cols wv*64..+63, rows h0..h0+1
    const float wx0 = (float)(wv * 64) * inv_c;
    const float wx1 = (float)(wv * 64 + 63) * inv_c;
    const float wy0 = (float)h0 * inv_c;
    const float wy1 = (float)(h0 + RPB - 1) * inv_c;

    int cnt = 0;
#pragma unroll
    for (int r = 0; r < 3; ++r) {
        const int n = r * 64 + lane;
        bool keep = false;
        float4 q;
        if (n < NPT) {
            q = base[n];                  // global, L1/L2-hot (20 KB total pd)
            float dxc = fmaxf(fmaxf(wx0 - q.x, q.x - wx1), 0.0f);
            float dyc = fmaxf(fmaxf(wy0 - q.y, q.y - wy1), 0.0f);
            keep = fmaf(dxc, dxc, dyc * dyc) < 1.0f;  // same float ops as body => safe
        }
        const unsigned long long mk = __ballot(keep);
        if (keep) {
            int pre = __popcll(mk & ((1ULL << lane) - 1ULL));
            wl[wv][cnt + pre] = q;
        }
        cnt += __popcll(mk);
    }
    const int padded = (cnt + 3) & ~3;    // pad with far-away zero-alpha dummies
    if (lane < padded - cnt) wl[wv][cnt + lane] = make_float4(1e9f, 1e9f, 0.0f, 0.0f);
    // same-wave ds write->read: ordered by lgkmcnt, no block barrier needed

    const float xs = (float)tid * inv_c;
    float acc0[RPB], acc1[RPB], ys[RPB];
#pragma unroll
    for (int k = 0; k < RPB; ++k) {
        acc0[k] = 0.0f;
        acc1[k] = 0.0f;
        ys[k] = (float)(h0 + k) * inv_c;
    }

    const float4* wlp = wl[wv];
#define BODY(q)                                                   \
    {                                                             \
        float dx = xs - (q).x;                                    \
        float dx2 = dx * dx;                                      \
        _Pragma("unroll")                                         \
        for (int k = 0; k < RPB; ++k) {                           \
            float dy = ys[k] - (q).y;                             \
            float d2 = fmaf(dy, dy, dx2);                         \
            float d = __builtin_amdgcn_sqrtf(d2);                 \
            float t = fmaxf(1.0f - d, 0.0f);                      \
            float g = fmaf(4.0f, d, 1.0f);                        \
            float t2 = t * t;                                     \
            float wgt = (t2 * t2) * g;                            \
            acc0[k] = fmaf(wgt, (q).z, acc0[k]);                  \
            acc1[k] = fmaf(wgt, (q).w, acc1[k]);                  \
        }                                                         \
    }

    for (int i = 0; i < padded; i += 4) {
        float4 q0 = wlp[i + 0];   // 4 broadcast ds_read_b128 in flight
        float4 q1 = wlp[i + 1];
        float4 q2 = wlp[i + 2];
        float4 q3 = wlp[i + 3];
        BODY(q0);
        BODY(q1);
        BODY(q2);
        BODY(q3);
    }
#undef BODY

    // out[((b*2 + c)*H + h)*W + x], coalesced across tid
#pragma unroll
    for (int k = 0; k < RPB; ++k) {
        const int h = h0 + k;
        out[((b * 2 + 0) * HGT + h) * WID + tid] = acc0[k];
        out[((b * 2 + 1) * HGT + h) * WID + tid] = acc1[k];
    }
}

extern "C" void kernel_launch(void* const* d_in, const int* in_sizes, int n_in,
                              void* d_out, int out_size, void* d_ws, size_t ws_size,
                              hipStream_t stream) {
    const float* cpoint = (const float*)d_in[0];  // [B, N, 2] f32
    const float* alpha  = (const float*)d_in[1];  // [B, N, 2] f32
    float4* pd  = (float4*)d_ws;                  // [B, N] packed normalized points
    float* invc = (float*)((char*)d_ws + NBATCH * NPT * sizeof(float4));
    float* out  = (float*)d_out;                  // [B, 2, H, W] f32

    rbf_prep_kernel<<<NBATCH, 256, 0, stream>>>(cpoint, alpha, pd, invc);
    rbf_eval_kernel<<<NBATCH * (HGT / RPB), 256, 0, stream>>>(pd, invc, out);
}

// Round 10
// 26.856 us; speedup vs baseline: 1.1559x; 1.0319x over previous
//
#include <hip/hip_runtime.h>

#define HGT 256
#define WID 256
#define NPT 160
#define NBATCH 8
#define RPB 2   // rows per thread

// Grid: 8 batches x (256/32 x-tiles) x (256/16 y-tiles) = 1024 blocks.
// Block: 4 waves; each wave owns a 16x8 pixel tile (square-ish => minimal
// dilated footprint => fewest cull survivors). Lane: col = lane&15,
// row-group = lane>>4 (2 rows each).

// d_ws layout: float4 pd[NBATCH][NPT] (px*ic, py*ic, a0, a1) | float inv_c[NBATCH]

// Pre-kernel (8 blocks): support radius + normalize + pack.
__global__ __launch_bounds__(256) void rbf_prep_kernel(const float* __restrict__ cpoint,
                                                       const float* __restrict__ alpha,
                                                       float4* __restrict__ pd,
                                                       float* __restrict__ invc) {
    const int b = blockIdx.x;
    const int tid = threadIdx.x;
    __shared__ float2 spts[NPT];
    __shared__ float sred[4];
    __shared__ float s_invc;

    const float2* cp2 = reinterpret_cast<const float2*>(cpoint) + b * NPT;
    const float2* al2 = reinterpret_cast<const float2*>(alpha) + b * NPT;

    if (tid < NPT) spts[tid] = cp2[tid];
    __syncthreads();

    float m = 0.0f;  // idle threads contribute 0 (all min-sq-dists >= 0)
    if (tid < NPT) {
        float minv = 1e10f;
        const float2 pi = spts[tid];
#pragma unroll 8
        for (int j = 0; j < NPT; ++j) {
            float dx = pi.x - spts[j].x;
            float dy = pi.y - spts[j].y;
            float s = fmaf(dy, dy, dx * dx);
            s = (j == tid) ? 1e10f : s;   // mask self-distance (reference: +eye*BIG)
            minv = fminf(minv, s);
        }
        m = minv;
    }
#pragma unroll
    for (int off = 32; off > 0; off >>= 1) m = fmaxf(m, __shfl_xor(m, off));
    if ((tid & 63) == 0) sred[tid >> 6] = m;
    __syncthreads();
    if (tid == 0) {
        float mm = fmaxf(fmaxf(sred[0], sred[1]), fmaxf(sred[2], sred[3]));
        s_invc = 1.0f / (2.0f * sqrtf(mm));
        invc[b] = s_invc;
    }
    __syncthreads();
    const float ic = s_invc;
    if (tid < NPT) {
        float2 p = spts[tid];
        float2 a = al2[tid];
        pd[b * NPT + tid] = make_float4(p.x * ic, p.y * ic, a.x, a.y);
    }
}

__global__ __launch_bounds__(256) void rbf_eval_kernel(const float4* __restrict__ pd,
                                                       const float* __restrict__ invc,
                                                       float* __restrict__ out) {
    const int tid = threadIdx.x;
    const int lane = tid & 63;
    const int wv = tid >> 6;              // 0..3
    const int bi = blockIdx.x;
    const int b = bi >> 7;                // 128 blocks per batch
    const int rem = bi & 127;
    const int ty = rem >> 3;              // 0..15  (16-row block tiles)
    const int tx = rem & 7;               // 0..7   (32-col block tiles)

    // wave tile origin: 2x2 waves inside the 32x16 block tile
    const int wx = tx * 32 + (wv & 1) * 16;   // 16 cols
    const int wy = ty * 16 + (wv >> 1) * 8;   // 8 rows

    const int col = lane & 15;
    const int rg = lane >> 4;             // 0..3, RPB rows each
    const int x = wx + col;
    const int y0 = wy + rg * RPB;

    __shared__ float4 wl[4][NPT + 4];     // per-wave compacted survivor list

    const float inv_c = invc[b];
    const float4* base = pd + b * NPT;

    // wave footprint in normalized coords
    const float wx0 = (float)wx * inv_c;
    const float wx1 = (float)(wx + 15) * inv_c;
    const float wy0 = (float)wy * inv_c;
    const float wy1 = (float)(wy + 7) * inv_c;

    int cnt = 0;
#pragma unroll
    for (int r = 0; r < 3; ++r) {
        const int n = r * 64 + lane;
        bool keep = false;
        float4 q;
        if (n < NPT) {
            q = base[n];                  // global, L1/L2-hot (20 KB total pd)
            float dxc = fmaxf(fmaxf(wx0 - q.x, q.x - wx1), 0.0f);
            float dyc = fmaxf(fmaxf(wy0 - q.y, q.y - wy1), 0.0f);
            keep = fmaf(dxc, dxc, dyc * dyc) < 1.0f;  // same float ops as body => safe
        }
        const unsigned long long mk = __ballot(keep);
        if (keep) {
            int pre = __popcll(mk & ((1ULL << lane) - 1ULL));
            wl[wv][cnt + pre] = q;
        }
        cnt += __popcll(mk);
    }
    const int padded = (cnt + 3) & ~3;    // pad with far-away zero-alpha dummies
    if (lane < padded - cnt) wl[wv][cnt + lane] = make_float4(1e9f, 1e9f, 0.0f, 0.0f);
    // same-wave ds write->read: ordered by lgkmcnt, no block barrier needed

    const float xs = (float)x * inv_c;
    float acc0[RPB], acc1[RPB], ys[RPB];
#pragma unroll
    for (int k = 0; k < RPB; ++k) {
        acc0[k] = 0.0f;
        acc1[k] = 0.0f;
        ys[k] = (float)(y0 + k) * inv_c;
    }

    const float4* wlp = wl[wv];
#define BODY(q)                                                   \
    {                                                             \
        float dx = xs - (q).x;                                    \
        float dx2 = dx * dx;                                      \
        _Pragma("unroll")                                         \
        for (int k = 0; k < RPB; ++k) {                           \
            float dy = ys[k] - (q).y;                             \
            float d2 = fmaf(dy, dy, dx2);                         \
            float d = __builtin_amdgcn_sqrtf(d2);                 \
            float t = fmaxf(1.0f - d, 0.0f);                      \
            float g = fmaf(4.0f, d, 1.0f);                        \
            float t2 = t * t;                                     \
            float wgt = (t2 * t2) * g;                            \
            acc0[k] = fmaf(wgt, (q).z, acc0[k]);                  \
            acc1[k] = fmaf(wgt, (q).w, acc1[k]);                  \
        }                                                         \
    }

    for (int i = 0; i < padded; i += 4) {
        float4 q0 = wlp[i + 0];   // 4 broadcast ds_read_b128 in flight
        float4 q1 = wlp[i + 1];
        float4 q2 = wlp[i + 2];
        float4 q3 = wlp[i + 3];
        BODY(q0);
        BODY(q1);
        BODY(q2);
        BODY(q3);
    }
#undef BODY

    // out[((b*2 + c)*H + y)*W + x]; 16-lane row segments (64B), 4 rows/inst
#pragma unroll
    for (int k = 0; k < RPB; ++k) {
        const int y = y0 + k;
        out[((b * 2 + 0) * HGT + y) * WID + x] = acc0[k];
        out[((b * 2 + 1) * HGT + y) * WID + x] = acc1[k];
    }
}

extern "C" void kernel_launch(void* const* d_in, const int* in_sizes, int n_in,
                              void* d_out, int out_size, void* d_ws, size_t ws_size,
                              hipStream_t stream) {
    const float* cpoint = (const float*)d_in[0];  // [B, N, 2] f32
    const float* alpha  = (const float*)d_in[1];  // [B, N, 2] f32
    float4* pd  = (float4*)d_ws;                  // [B, N] packed normalized points
    float* invc = (float*)((char*)d_ws + NBATCH * NPT * sizeof(float4));
    float* out  = (float*)d_out;                  // [B, 2, H, W] f32

    rbf_prep_kernel<<<NBATCH, 256, 0, stream>>>(cpoint, alpha, pd, invc);
    rbf_eval_kernel<<<1024, 256, 0, stream>>>(pd, invc, out);
}